// Round 2
// baseline (2432.485 us; speedup 1.0000x reference)
//
#include <hip/hip_runtime.h>

// DGMC top-k correspondence, MI355X.
// Phase 1: fused fp32 GEMM (S = h_s @ h_t^T) + per-partition running top-10.
// Phase 2: per-row merge of partition partials -> top-12 candidate indices.
// Phase 3: f64 re-evaluation of the 12 candidates, exact sort, softmax, write.
// Outputs: [eS0 | rS0 | eidx | ridx], each 10000*10 floats (idx as float).

struct Pair { float v; int i; };

#define K_TOP 10
#define CAND_M 12
#define BM 128
#define BN 128
#define KC 32
#define CDIM 256

#define GLD_LDS(src, dst) \
    __builtin_amdgcn_global_load_lds((const __attribute__((address_space(1))) void*)(src), \
                                     (__attribute__((address_space(3))) void*)(dst), 16, 0, 0)

template <int K>
__device__ __forceinline__ void topk_insert(float (&tv)[K], int (&ti)[K],
                                            float &tmin, float v, int t) {
    // find current min slot (on value ties, evict the HIGHER index)
    float mv = tv[0]; int mi = ti[0]; int mp = 0;
#pragma unroll
    for (int q = 1; q < K; ++q) {
        bool b = (tv[q] < mv) || (tv[q] == mv && ti[q] > mi);
        if (b) { mv = tv[q]; mi = ti[q]; mp = q; }
    }
#pragma unroll
    for (int q = 0; q < K; ++q)
        if (q == mp) { tv[q] = v; ti[q] = t; }
    float nm = tv[0];
#pragma unroll
    for (int q = 1; q < K; ++q) nm = fminf(nm, tv[q]);
    tmin = nm;
}

// LDS: A chunk 128x32 f32 (4096), B chunk 128x32 f32 (4096), S tile 128x68 (8704)
// total 16896 f32 = 67.6 KB -> 2 blocks/CU.
__global__ __launch_bounds__(256, 2) void topk_gemm(
    const float* __restrict__ ehs, const float* __restrict__ eht,
    const float* __restrict__ rhs_, const float* __restrict__ rht,
    Pair* __restrict__ partials,
    int Ns, int Nt, int P, int RB, int PS)
{
    __shared__ float lds[16896];
    float* Alds = lds;
    float* Blds = lds + 4096;
    float* Slds = lds + 8192;

    const int tid = threadIdx.x;
    const int tx = tid & 15, ty = tid >> 4;

    int bid = blockIdx.x;
    const int prob = bid / (P * RB);
    const int r2   = bid % (P * RB);
    const int p    = r2 / RB;
    const int rbi  = r2 % RB;

    const float* hs = prob ? rhs_ : ehs;
    const float* ht = prob ? rht  : eht;

    const int rb = rbi * BM;
    const int t0 = p * PS;
    const int t1 = min(t0 + PS, Nt);

    float tv[K_TOP]; int ti[K_TOP]; float tmin = -3.4e38f;
#pragma unroll
    for (int q = 0; q < K_TOP; ++q) { tv[q] = -3.4e38f; ti[q] = 0x7FFFFFFF; }

    const int scan_row = tid >> 1;
    const int scan_sub = tid & 1;
    const int wbase = tid & ~63;

    for (int tb = t0; tb < t1; tb += BN) {
        float acc[8][8];
#pragma unroll
        for (int i = 0; i < 8; ++i)
#pragma unroll
            for (int j = 0; j < 8; ++j) acc[i][j] = 0.f;

#pragma unroll 1
        for (int ck = 0; ck < CDIM / KC; ++ck) {
            const int kc0 = ck * KC;
            __syncthreads();   // previous readers of Alds/Blds are done
            // stage A chunk (rows rb..rb+127, k = kc0..kc0+31), XOR-swizzled source
#pragma unroll
            for (int it = 0; it < 4; ++it) {
                int slot = it * 256 + tid;
                int row = slot >> 3, kgd = slot & 7;
                int kgs = kgd ^ ((row >> 3) & 7);
                int gr = rb + row; gr = gr < Ns ? gr : Ns - 1;
                const float* src = hs + (size_t)gr * CDIM + kc0 + kgs * 4;
                GLD_LDS(src, Alds + (it * 256 + wbase) * 4);
            }
            // stage B chunk (rows tb..tb+127)
#pragma unroll
            for (int it = 0; it < 4; ++it) {
                int slot = it * 256 + tid;
                int row = slot >> 3, kgd = slot & 7;
                int kgs = kgd ^ ((row >> 3) & 7);
                int gt = tb + row; gt = gt < Nt ? gt : Nt - 1;
                const float* src = ht + (size_t)gt * CDIM + kc0 + kgs * 4;
                GLD_LDS(src, Blds + (it * 256 + wbase) * 4);
            }
            __syncthreads();   // drains vmcnt then barrier

#pragma unroll
            for (int kg = 0; kg < KC / 4; ++kg) {
                float4 av[8], bv[8];
                const int ao = ((kg ^ (ty & 7)) << 2);
#pragma unroll
                for (int i = 0; i < 8; ++i)
                    av[i] = *(const float4*)&Alds[(ty * 8 + i) * KC + ao];
                const int bo = ((kg ^ (tx & 7)) << 2);
#pragma unroll
                for (int j = 0; j < 8; ++j)
                    bv[j] = *(const float4*)&Blds[(tx * 8 + j) * KC + bo];
#pragma unroll
                for (int i = 0; i < 8; ++i)
#pragma unroll
                    for (int j = 0; j < 8; ++j) {
                        acc[i][j] = fmaf(av[i].x, bv[j].x, acc[i][j]);
                        acc[i][j] = fmaf(av[i].y, bv[j].y, acc[i][j]);
                        acc[i][j] = fmaf(av[i].z, bv[j].z, acc[i][j]);
                        acc[i][j] = fmaf(av[i].w, bv[j].w, acc[i][j]);
                    }
            }
        }

        // ---- top-k scan: flush S tile through LDS in two column-halves ----
#pragma unroll
        for (int h = 0; h < 2; ++h) {
            __syncthreads();   // previous scan readers of Slds are done
            if ((tx >> 3) == h) {
                const int cl = (tx & 7) * 8;
#pragma unroll
                for (int i = 0; i < 8; ++i) {
                    float4 v0 = make_float4(acc[i][0], acc[i][1], acc[i][2], acc[i][3]);
                    float4 v1 = make_float4(acc[i][4], acc[i][5], acc[i][6], acc[i][7]);
                    *(float4*)&Slds[(ty * 8 + i) * 68 + cl]     = v0;
                    *(float4*)&Slds[(ty * 8 + i) * 68 + cl + 4] = v1;
                }
            }
            __syncthreads();
            const int tbase = tb + h * 64 + scan_sub * 32;
#pragma unroll 2
            for (int g = 0; g < 8; ++g) {
                float4 v = *(const float4*)&Slds[scan_row * 68 + scan_sub * 32 + g * 4];
                int t = tbase + g * 4;
                if (t + 0 < t1 && v.x > tmin) topk_insert<K_TOP>(tv, ti, tmin, v.x, t + 0);
                if (t + 1 < t1 && v.y > tmin) topk_insert<K_TOP>(tv, ti, tmin, v.y, t + 1);
                if (t + 2 < t1 && v.z > tmin) topk_insert<K_TOP>(tv, ti, tmin, v.z, t + 2);
                if (t + 3 < t1 && v.w > tmin) topk_insert<K_TOP>(tv, ti, tmin, v.w, t + 3);
            }
        }
    }

    // ---- block-level merge of the 2 per-row states, write partition partials ----
    __syncthreads();
    {
        float* SV = Slds;                    // 128*20 floats
        int*   SI = (int*)(Slds + 2560);     // 128*20 ints
#pragma unroll
        for (int q = 0; q < K_TOP; ++q) {
            SV[scan_row * 20 + scan_sub * 10 + q] = tv[q];
            SI[scan_row * 20 + scan_sub * 10 + q] = ti[q];
        }
        __syncthreads();
        if (tid < BM && rb + tid < Ns) {
            const int grow = rb + tid;
            float cv[20]; int ci[20];
#pragma unroll
            for (int q = 0; q < 20; ++q) { cv[q] = SV[tid * 20 + q]; ci[q] = SI[tid * 20 + q]; }
            Pair* wp = partials + (((size_t)prob * Ns + grow) * P + p) * K_TOP;
#pragma unroll
            for (int o = 0; o < K_TOP; ++o) {
                float bv2 = cv[0]; int bi = ci[0]; int bp = 0;
#pragma unroll
                for (int q = 1; q < 20; ++q) {
                    bool better = (cv[q] > bv2) || (cv[q] == bv2 && ci[q] < bi);
                    if (better) { bv2 = cv[q]; bi = ci[q]; bp = q; }
                }
                wp[o].v = bv2; wp[o].i = bi;
#pragma unroll
                for (int q = 0; q < 20; ++q) if (q == bp) cv[q] = -3.4e38f;
            }
        }
    }
}

// Per row: merge P*10 fp32 partials -> top-CAND_M candidate indices (membership only).
__global__ void topk_mergecand(const Pair* __restrict__ partials, int* __restrict__ cand,
                               int Ns, int P, int M)
{
    int g = blockIdx.x * blockDim.x + threadIdx.x;
    if (g >= 2 * Ns) return;
    const Pair* src = partials + (size_t)g * P * K_TOP;

    float tv[CAND_M]; int ti[CAND_M]; float tmin = -3.4e38f;
#pragma unroll
    for (int q = 0; q < CAND_M; ++q) { tv[q] = -3.4e38f; ti[q] = 0x7FFFFFFF; }
    for (int q = 0; q < P * K_TOP; ++q) {
        Pair pr = src[q];
        if (pr.v > tmin) topk_insert<CAND_M>(tv, ti, tmin, pr.v, pr.i);
    }
    int* dst = cand + (size_t)g * CAND_M;
#pragma unroll
    for (int q = 0; q < CAND_M; ++q) dst[q] = ti[q];
    (void)M;
}

// One wave per row: recompute the M candidate dots in fp64, exact ordering,
// fp32 softmax, write values + indices.
__global__ __launch_bounds__(256) void topk_refine(
    const float* __restrict__ ehs, const float* __restrict__ eht,
    const float* __restrict__ rhs_, const float* __restrict__ rht,
    const int* __restrict__ cand, float* __restrict__ out, int Ns, int M)
{
    const int wid  = (int)((blockIdx.x * (size_t)blockDim.x + threadIdx.x) >> 6);
    const int lane = threadIdx.x & 63;
    if (wid >= 2 * Ns) return;
    const int prob = wid < Ns ? 0 : 1;
    const int row  = prob ? (wid - Ns) : wid;
    const float* hs = prob ? rhs_ : ehs;
    const float* ht = prob ? rht  : eht;

    float4 a = *(const float4*)&hs[(size_t)row * CDIM + lane * 4];
    const double a0 = a.x, a1 = a.y, a2 = a.z, a3 = a.w;

    double vd[CAND_M]; int ci[CAND_M];
#pragma unroll
    for (int m = 0; m < CAND_M; ++m) { vd[m] = -1.0e300; ci[m] = 0x7FFFFFFF; }

    const int* cbase = cand + (size_t)wid * CAND_M;
#pragma unroll
    for (int m = 0; m < CAND_M; ++m) {
        if (m < M) {
            int t = cbase[m];
            ci[m] = t;
            float4 b = *(const float4*)&ht[(size_t)t * CDIM + lane * 4];
            double s = a0 * (double)b.x + a1 * (double)b.y
                     + a2 * (double)b.z + a3 * (double)b.w;
#pragma unroll
            for (int d = 1; d < 64; d <<= 1) s += __shfl_xor(s, d, 64);
            vd[m] = s;
        }
    }

    if (lane == 0) {
        float ov[K_TOP]; int oi[K_TOP];
#pragma unroll
        for (int o = 0; o < K_TOP; ++o) {
            double bv = vd[0]; int bi = ci[0]; int bp = 0;
#pragma unroll
            for (int q = 1; q < CAND_M; ++q) {
                bool better = (vd[q] > bv) || (vd[q] == bv && ci[q] < bi);
                if (better) { bv = vd[q]; bi = ci[q]; bp = q; }
            }
            ov[o] = (float)bv; oi[o] = bi;
#pragma unroll
            for (int q = 0; q < CAND_M; ++q) if (q == bp) vd[q] = -1.0e301;
        }
        float m0 = ov[0], ssum = 0.f, ex[K_TOP];
#pragma unroll
        for (int q = 0; q < K_TOP; ++q) { ex[q] = __expf(ov[q] - m0); ssum += ex[q]; }
        float inv = 1.f / ssum;
        size_t nsk = (size_t)Ns * K_TOP;
        size_t so  = (size_t)wid * K_TOP;   // == (prob*Ns + row)*K_TOP
#pragma unroll
        for (int q = 0; q < K_TOP; ++q) out[so + q] = ex[q] * inv;
#pragma unroll
        for (int q = 0; q < K_TOP; ++q) out[2 * nsk + so + q] = (float)oi[q];
    }
}

extern "C" void kernel_launch(void* const* d_in, const int* in_sizes, int n_in,
                              void* d_out, int out_size, void* d_ws, size_t ws_size,
                              hipStream_t stream) {
    (void)n_in; (void)out_size;
    const float* eh_s = (const float*)d_in[0];
    const float* eh_t = (const float*)d_in[1];
    const float* rh_s = (const float*)d_in[2];
    const float* rh_t = (const float*)d_in[3];
    // k (d_in[4]) is a device scalar; it is 10 for this problem.

    const int C  = CDIM;
    const int Ns = in_sizes[0] / C;
    const int Nt = in_sizes[1] / C;
    const int RB = (Ns + BM - 1) / BM;

    const size_t candBytes = (size_t)2 * Ns * CAND_M * sizeof(int);
    int P = 16;
    while (P > 1 &&
           (size_t)2 * Ns * P * K_TOP * sizeof(Pair) + candBytes > ws_size) P >>= 1;
    const int PS = (Nt + P - 1) / P;
    const int M  = (P * K_TOP < CAND_M) ? P * K_TOP : CAND_M;

    Pair* partials = (Pair*)d_ws;
    int*  cand     = (int*)((char*)d_ws + (size_t)2 * Ns * P * K_TOP * sizeof(Pair));

    dim3 block(256);
    topk_gemm<<<dim3(2 * P * RB), block, 0, stream>>>(eh_s, eh_t, rh_s, rh_t,
                                                      partials, Ns, Nt, P, RB, PS);

    int nrows = 2 * Ns;
    topk_mergecand<<<dim3((nrows + 255) / 256), block, 0, stream>>>(partials, cand,
                                                                    Ns, P, M);

    int refineBlocks = (nrows * 64 + 255) / 256;
    topk_refine<<<dim3(refineBlocks), block, 0, stream>>>(eh_s, eh_t, rh_s, rh_t,
                                                          cand, (float*)d_out, Ns, M);
}

// Round 3
// 1299.918 us; speedup vs baseline: 1.8713x; 1.8713x over previous
//
#include <hip/hip_runtime.h>

// DGMC top-k correspondence, MI355X — bf16 MFMA candidate GEMM + f64 refine.
// Phase 0: convert h_t fp32 -> bf16, granule-swizzled (phys g holds logical g^(row&31)).
// Phase 1: S^T tiles via mfma_f32_32x32x16_bf16 (A=h_t from LDS, B=h_s in regs),
//          per-lane running top-10 per s-column, partials per t-partition.
// Phase 2: per-row merge of partials -> top-16 candidate indices.
// Phase 3: f64 re-evaluation of candidates (original fp32 inputs), exact sort,
//          softmax, write [eS0 | rS0 | eidx | ridx] (idx as float).

typedef __attribute__((ext_vector_type(8)))  short bf16x8;
typedef __attribute__((ext_vector_type(16))) float f32x16;
typedef __attribute__((ext_vector_type(8)))  unsigned short u16x8;

struct Pair { float v; int i; };

#define K_TOP 10
#define CAND_M 16
#define CDIM 256

#define GLD_LDS(src, dst) \
    __builtin_amdgcn_global_load_lds((const __attribute__((address_space(1))) void*)(src), \
                                     (__attribute__((address_space(3))) void*)(dst), 16, 0, 0)

__device__ __forceinline__ unsigned short f2bf(float f) {
    unsigned u = __float_as_uint(f);
    u += 0x7fffu + ((u >> 16) & 1u);      // RNE
    return (unsigned short)(u >> 16);
}

template <int K>
__device__ __forceinline__ void topk_insert(float (&tv)[K], int (&ti)[K],
                                            float &tmin, float v, int t) {
    float mv = tv[0]; int mi = ti[0]; int mp = 0;
#pragma unroll
    for (int q = 1; q < K; ++q) {
        bool b = (tv[q] < mv) || (tv[q] == mv && ti[q] > mi);
        if (b) { mv = tv[q]; mi = ti[q]; mp = q; }
    }
#pragma unroll
    for (int q = 0; q < K; ++q)
        if (q == mp) { tv[q] = v; ti[q] = t; }
    float nm = tv[0];
#pragma unroll
    for (int q = 1; q < K; ++q) nm = fminf(nm, tv[q]);
    tmin = nm;
}

// ---------- Phase 0: fp32 -> bf16 with per-row granule XOR swizzle ----------
__global__ void conv_swz(const float* __restrict__ in, unsigned short* __restrict__ out, int N)
{
    int gid = blockIdx.x * blockDim.x + threadIdx.x;
    int row = gid >> 5, gl = gid & 31;
    if (row >= N) return;
    const float4* src = (const float4*)(in + (size_t)row * CDIM + gl * 8);
    float4 a0 = src[0], a1 = src[1];
    u16x8 o;
    o[0] = f2bf(a0.x); o[1] = f2bf(a0.y); o[2] = f2bf(a0.z); o[3] = f2bf(a0.w);
    o[4] = f2bf(a1.x); o[5] = f2bf(a1.y); o[6] = f2bf(a1.z); o[7] = f2bf(a1.w);
    *(u16x8*)(out + (size_t)row * CDIM + ((gl ^ (row & 31)) * 8)) = o;
}

// ---------- Phase 1: MFMA GEMM + per-lane top-10 ----------
__device__ __forceinline__ void stage64(const unsigned short* __restrict__ htb,
                                        short* ldsbuf, int tbase, int Nt,
                                        int tid, int wbase) {
#pragma unroll
    for (int it = 0; it < 8; ++it) {
        int pp = it * 256 + tid;
        int rr = pp >> 5, gg = pp & 31;
        int grow = tbase + rr; grow = grow < Nt ? grow : Nt - 1;
        GLD_LDS(htb + (size_t)grow * CDIM + gg * 8, ldsbuf + (it * 256 + wbase) * 8);
    }
}

// block = 256 thr = 4 waves; wave w owns 32 s-cols (block spans 128 s).
// LDS: 2 x (64 t-rows x 256 bf16) = 64 KB double buffer.
__global__ __launch_bounds__(256, 2) void topk_mfma(
    const float* __restrict__ ehs, const float* __restrict__ rhs_,
    const unsigned short* __restrict__ ehtb, const unsigned short* __restrict__ rhtb,
    Pair* __restrict__ partials, int Ns, int Nt, int Pt, int SB, int PS)
{
    __shared__ short ldsT[2 * 64 * 256];

    const int tid = threadIdx.x;
    const int w = tid >> 6, lane = tid & 63;
    const int l5 = lane & 31, hi = lane >> 5;
    const int wbase = tid & ~63;

    const int bid  = blockIdx.x;
    const int prob = bid / (Pt * SB);
    const int rem  = bid % (Pt * SB);
    const int p    = rem / SB, sb = rem % SB;

    const float* hs = prob ? rhs_ : ehs;
    const unsigned short* htb = prob ? rhtb : ehtb;

    const int srow = sb * 128 + w * 32 + l5;
    const int srd  = srow < Ns ? srow : Ns - 1;

    // B-panel: h_s[srd][kk*16 + hi*8 + j], j=0..7 -> 16 frags (64 VGPRs), persistent.
    bf16x8 b[16];
#pragma unroll
    for (int kk = 0; kk < 16; ++kk) {
        const float4* sp = (const float4*)(hs + (size_t)srd * CDIM + kk * 16 + hi * 8);
        float4 f0 = sp[0], f1 = sp[1];
        bf16x8 t;
        t[0] = (short)f2bf(f0.x); t[1] = (short)f2bf(f0.y);
        t[2] = (short)f2bf(f0.z); t[3] = (short)f2bf(f0.w);
        t[4] = (short)f2bf(f1.x); t[5] = (short)f2bf(f1.y);
        t[6] = (short)f2bf(f1.z); t[7] = (short)f2bf(f1.w);
        b[kk] = t;
    }

    const int t0 = p * PS;
    const int t1 = min(t0 + PS, Nt);

    float tv[K_TOP]; int ti[K_TOP]; float tmin = -3.4e38f;
#pragma unroll
    for (int q = 0; q < K_TOP; ++q) { tv[q] = -3.4e38f; ti[q] = 0x7FFFFFFF; }

    const int rounds = (t1 > t0) ? ((t1 - t0 + 63) >> 6) : 0;

    if (rounds > 0) {
        stage64(htb, ldsT, t0, Nt, tid, wbase);
        __syncthreads();

        for (int rd = 0; rd < rounds; ++rd) {
            const int cur = rd & 1;
            const int tb  = t0 + rd * 64;
            if (rd + 1 < rounds)
                stage64(htb, ldsT + (cur ^ 1) * 16384, tb + 64, Nt, tid, wbase);

            const short* lb = ldsT + cur * 16384;
#pragma unroll
            for (int tt = 0; tt < 2; ++tt) {
                f32x16 acc = {};
                const short* rowp = lb + (tt * 32 + l5) * CDIM;
#pragma unroll
                for (int kk = 0; kk < 16; ++kk) {
                    // A-frag: row = l5 (t-local), k = kk*16 + hi*8 + j; unswizzle granule
                    bf16x8 a = *(const bf16x8*)(rowp + (((kk * 2 + hi) ^ l5) * 8));
                    acc = __builtin_amdgcn_mfma_f32_32x32x16_bf16(a, b[kk], acc, 0, 0, 0);
                }
                // ---- scan 16 acc values (one s-col per lane) ----
                float m0 = fmaxf(fmaxf(acc[0], acc[1]),  fmaxf(acc[2], acc[3]));
                float m1 = fmaxf(fmaxf(acc[4], acc[5]),  fmaxf(acc[6], acc[7]));
                float m2 = fmaxf(fmaxf(acc[8], acc[9]),  fmaxf(acc[10], acc[11]));
                float m3 = fmaxf(fmaxf(acc[12], acc[13]), fmaxf(acc[14], acc[15]));
                float mx = fmaxf(fmaxf(m0, m1), fmaxf(m2, m3));
                if (mx > tmin) {
                    const int tb2 = tb + tt * 32 + 4 * hi;
#pragma unroll
                    for (int r = 0; r < 16; ++r) {
                        float v = acc[r];
                        int t = tb2 + (r & 3) + 8 * (r >> 2);
                        if (v > tmin && t < t1)
                            topk_insert<K_TOP>(tv, ti, tmin, v, t);
                    }
                }
            }
            __syncthreads();
        }
    }

    if (srow < Ns) {
        Pair* wp = partials + (((size_t)prob * Ns + srow) * (2 * Pt) + (p * 2 + hi)) * K_TOP;
#pragma unroll
        for (int q = 0; q < K_TOP; ++q) { wp[q].v = tv[q]; wp[q].i = ti[q]; }
    }
}

// ---------- Phase 2: merge chains -> top-16 candidate indices ----------
__global__ void topk_mergecand(const Pair* __restrict__ partials, int* __restrict__ cand,
                               int Ns, int CH)
{
    int g = blockIdx.x * blockDim.x + threadIdx.x;
    if (g >= 2 * Ns) return;
    const Pair* src = partials + (size_t)g * CH * K_TOP;

    float tv[CAND_M]; int ti[CAND_M]; float tmin = -3.4e38f;
#pragma unroll
    for (int q = 0; q < CAND_M; ++q) { tv[q] = -3.4e38f; ti[q] = 0x7FFFFFFF; }
    for (int q = 0; q < CH * K_TOP; ++q) {
        Pair pr = src[q];
        if (pr.v > tmin) topk_insert<CAND_M>(tv, ti, tmin, pr.v, pr.i);
    }
    int* dst = cand + (size_t)g * CAND_M;
#pragma unroll
    for (int q = 0; q < CAND_M; ++q) dst[q] = ti[q];
}

// ---------- Phase 3: f64 refine, exact sort, softmax, write ----------
__global__ __launch_bounds__(256) void topk_refine(
    const float* __restrict__ ehs, const float* __restrict__ eht,
    const float* __restrict__ rhs_, const float* __restrict__ rht,
    const int* __restrict__ cand, float* __restrict__ out, int Ns, int Nt)
{
    const int wid  = (int)((blockIdx.x * (size_t)blockDim.x + threadIdx.x) >> 6);
    const int lane = threadIdx.x & 63;
    if (wid >= 2 * Ns) return;
    const int prob = wid < Ns ? 0 : 1;
    const int row  = prob ? (wid - Ns) : wid;
    const float* hs = prob ? rhs_ : ehs;
    const float* ht = prob ? rht  : eht;

    float4 a = *(const float4*)&hs[(size_t)row * CDIM + lane * 4];
    const double a0 = a.x, a1 = a.y, a2 = a.z, a3 = a.w;

    double vd[CAND_M]; int ci[CAND_M];
#pragma unroll
    for (int m = 0; m < CAND_M; ++m) { vd[m] = -1.0e300; ci[m] = 0x7FFFFFFF; }

    const int* cbase = cand + (size_t)wid * CAND_M;
#pragma unroll
    for (int m = 0; m < CAND_M; ++m) {
        int t = cbase[m];
        if (t >= 0 && t < Nt) {
            ci[m] = t;
            float4 bb = *(const float4*)&ht[(size_t)t * CDIM + lane * 4];
            double s = a0 * (double)bb.x + a1 * (double)bb.y
                     + a2 * (double)bb.z + a3 * (double)bb.w;
#pragma unroll
            for (int d = 1; d < 64; d <<= 1) s += __shfl_xor(s, d, 64);
            vd[m] = s;
        }
    }

    if (lane == 0) {
        float ov[K_TOP]; int oi[K_TOP];
#pragma unroll
        for (int o = 0; o < K_TOP; ++o) {
            double bv = vd[0]; int bi = ci[0]; int bp = 0;
#pragma unroll
            for (int q = 1; q < CAND_M; ++q) {
                bool better = (vd[q] > bv) || (vd[q] == bv && ci[q] < bi);
                if (better) { bv = vd[q]; bi = ci[q]; bp = q; }
            }
            ov[o] = (float)bv; oi[o] = bi;
#pragma unroll
            for (int q = 0; q < CAND_M; ++q) if (q == bp) vd[q] = -1.0e301;
        }
        float m0 = ov[0], ssum = 0.f, ex[K_TOP];
#pragma unroll
        for (int q = 0; q < K_TOP; ++q) { ex[q] = __expf(ov[q] - m0); ssum += ex[q]; }
        float inv = 1.f / ssum;
        size_t nsk = (size_t)Ns * K_TOP;
        size_t so  = (size_t)wid * K_TOP;
#pragma unroll
        for (int q = 0; q < K_TOP; ++q) out[so + q] = ex[q] * inv;
#pragma unroll
        for (int q = 0; q < K_TOP; ++q) out[2 * nsk + so + q] = (float)oi[q];
    }
}

extern "C" void kernel_launch(void* const* d_in, const int* in_sizes, int n_in,
                              void* d_out, int out_size, void* d_ws, size_t ws_size,
                              hipStream_t stream) {
    (void)n_in; (void)out_size;
    const float* eh_s = (const float*)d_in[0];
    const float* eh_t = (const float*)d_in[1];
    const float* rh_s = (const float*)d_in[2];
    const float* rh_t = (const float*)d_in[3];
    // d_in[4] is k (=10), compile-time constant here.

    const int Ns = in_sizes[0] / CDIM;
    const int Nt = in_sizes[1] / CDIM;
    const int SB = (Ns + 127) / 128;

    const size_t htbElems = (size_t)Nt * CDIM;          // per array, ushorts
    const size_t htbBytes = 2 * htbElems * 2;
    const size_t candBytes = (size_t)2 * Ns * CAND_M * sizeof(int);

    int Pt = 8;
    while (Pt > 1 &&
           htbBytes + (size_t)2 * Ns * (2 * Pt) * K_TOP * sizeof(Pair) + candBytes > ws_size)
        Pt >>= 1;
    const int PS = (int)((((size_t)Nt + Pt - 1) / Pt + 63) & ~(size_t)63);

    unsigned short* htb_e = (unsigned short*)d_ws;
    unsigned short* htb_r = htb_e + htbElems;
    Pair* partials = (Pair*)(htb_r + htbElems);
    int*  cand     = (int*)((char*)partials + (size_t)2 * Ns * (2 * Pt) * K_TOP * sizeof(Pair));

    dim3 block(256);

    // Phase 0: convert both h_t arrays (swizzled bf16)
    int convBlocks = (Nt * 32 + 255) / 256;
    conv_swz<<<dim3(convBlocks), block, 0, stream>>>(eh_t, htb_e, Nt);
    conv_swz<<<dim3(convBlocks), block, 0, stream>>>(rh_t, htb_r, Nt);

    // Phase 1: MFMA GEMM + top-10 chains
    topk_mfma<<<dim3(2 * Pt * SB), block, 0, stream>>>(eh_s, rh_s, htb_e, htb_r,
                                                       partials, Ns, Nt, Pt, SB, PS);

    // Phase 2: merge -> candidates
    int nrows = 2 * Ns;
    topk_mergecand<<<dim3((nrows + 255) / 256), block, 0, stream>>>(partials, cand,
                                                                    Ns, 2 * Pt);

    // Phase 3: f64 refine + softmax + write
    int refineBlocks = (nrows * 64 + 255) / 256;
    topk_refine<<<dim3(refineBlocks), block, 0, stream>>>(eh_s, eh_t, rh_s, rh_t,
                                                          cand, (float*)d_out, Ns, Nt);
}

// Round 4
// 389.212 us; speedup vs baseline: 6.2498x; 3.3399x over previous
//
#include <hip/hip_runtime.h>

// DGMC top-k correspondence, MI355X — bf16 MFMA candidate GEMM + f64 refine.
// Phase 0: convert h_t fp32 -> bf16, granule-swizzled (phys g holds logical g^(row&31)).
// Phase 1: S^T tiles via mfma_f32_32x32x16_bf16 (A=h_t from LDS, B=h_s in regs).
//          Per-lane top-10 kept as SORTED PACKED uints: key = (ordered_f32 & ~0x3FFF) | t.
//          Extract-max while-loop -> work scales with actual inserts, not values.
// Phase 2: per-row merge of packed chains -> top-16 candidate indices.
// Phase 3: f64 re-evaluation of candidates (original fp32 inputs), exact sort,
//          softmax, write [eS0 | rS0 | eidx | ridx] (idx as float).

typedef __attribute__((ext_vector_type(8)))  short bf16x8;
typedef __attribute__((ext_vector_type(16))) float f32x16;
typedef __attribute__((ext_vector_type(8)))  unsigned short u16x8;

#define K_TOP 10
#define CAND_M 16
#define CDIM 256

#define GLD_LDS(src, dst) \
    __builtin_amdgcn_global_load_lds((const __attribute__((address_space(1))) void*)(src), \
                                     (__attribute__((address_space(3))) void*)(dst), 16, 0, 0)

__device__ __forceinline__ unsigned short f2bf(float f) {
    unsigned u = __float_as_uint(f);
    u += 0x7fffu + ((u >> 16) & 1u);      // RNE
    return (unsigned short)(u >> 16);
}

__device__ __forceinline__ unsigned umax2(unsigned a, unsigned b) { return a > b ? a : b; }

__device__ __forceinline__ unsigned umax16(const unsigned (&p)[16]) {
    unsigned a = umax2(umax2(umax2(p[0], p[1]), umax2(p[2], p[3])),
                       umax2(umax2(p[4], p[5]), umax2(p[6], p[7])));
    unsigned b = umax2(umax2(umax2(p[8], p[9]), umax2(p[10], p[11])),
                       umax2(umax2(p[12], p[13]), umax2(p[14], p[15])));
    return umax2(a, b);
}

// Branchless ripple-insert of v into descending-sorted tv. No-op when v <= tv[K-1].
template <int K>
__device__ __forceinline__ void sorted_insert(unsigned (&tv)[K], unsigned v) {
    bool m[K];
#pragma unroll
    for (int q = 0; q < K; ++q) m[q] = tv[q] >= v;
    unsigned nv[K];
    nv[0] = m[0] ? tv[0] : v;
#pragma unroll
    for (int q = 1; q < K; ++q)
        nv[q] = m[q] ? tv[q] : (m[q - 1] ? v : tv[q - 1]);
#pragma unroll
    for (int q = 0; q < K; ++q) tv[q] = nv[q];
}

// ---------- Phase 0: fp32 -> bf16 with per-row granule XOR swizzle ----------
__global__ void conv_swz(const float* __restrict__ in, unsigned short* __restrict__ out, int N)
{
    int gid = blockIdx.x * blockDim.x + threadIdx.x;
    int row = gid >> 5, gl = gid & 31;
    if (row >= N) return;
    const float4* src = (const float4*)(in + (size_t)row * CDIM + gl * 8);
    float4 a0 = src[0], a1 = src[1];
    u16x8 o;
    o[0] = f2bf(a0.x); o[1] = f2bf(a0.y); o[2] = f2bf(a0.z); o[3] = f2bf(a0.w);
    o[4] = f2bf(a1.x); o[5] = f2bf(a1.y); o[6] = f2bf(a1.z); o[7] = f2bf(a1.w);
    *(u16x8*)(out + (size_t)row * CDIM + ((gl ^ (row & 31)) * 8)) = o;
}

// ---------- Phase 1: MFMA GEMM + per-lane packed top-10 ----------
__device__ __forceinline__ void stage64(const unsigned short* __restrict__ htb,
                                        short* ldsbuf, int tbase, int Nt,
                                        int tid, int wbase) {
#pragma unroll
    for (int it = 0; it < 8; ++it) {
        int pp = it * 256 + tid;
        int rr = pp >> 5, gg = pp & 31;
        int grow = tbase + rr; grow = grow < Nt ? grow : Nt - 1;
        GLD_LDS(htb + (size_t)grow * CDIM + gg * 8, ldsbuf + (it * 256 + wbase) * 8);
    }
}

// block = 256 thr = 4 waves; wave w owns 32 s-cols (block spans 128 s).
// LDS: 2 x (64 t-rows x 256 bf16) = 64 KB double buffer -> 2 blocks/CU.
__global__ __launch_bounds__(256, 2) void topk_mfma(
    const float* __restrict__ ehs, const float* __restrict__ rhs_,
    const unsigned short* __restrict__ ehtb, const unsigned short* __restrict__ rhtb,
    unsigned* __restrict__ partials, int Ns, int Nt, int Pt, int SB, int PS)
{
    __shared__ short ldsT[2 * 64 * 256];

    const int tid = threadIdx.x;
    const int w = tid >> 6, lane = tid & 63;
    const int l5 = lane & 31, hi = lane >> 5;
    const int wbase = tid & ~63;
    const int CH = 2 * Pt;

    const int bid  = blockIdx.x;
    const int prob = bid / (Pt * SB);
    const int rem  = bid % (Pt * SB);
    const int p    = rem / SB, sb = rem % SB;

    const float* hs = prob ? rhs_ : ehs;
    const unsigned short* htb = prob ? rhtb : ehtb;

    const int srow = sb * 128 + w * 32 + l5;
    const int srd  = srow < Ns ? srow : Ns - 1;

    // B-panel: h_s[srd][kk*16 + hi*8 + j], j=0..7 -> 16 frags (64 VGPRs), persistent.
    bf16x8 b[16];
#pragma unroll
    for (int kk = 0; kk < 16; ++kk) {
        const float4* sp = (const float4*)(hs + (size_t)srd * CDIM + kk * 16 + hi * 8);
        float4 f0 = sp[0], f1 = sp[1];
        bf16x8 t;
        t[0] = (short)f2bf(f0.x); t[1] = (short)f2bf(f0.y);
        t[2] = (short)f2bf(f0.z); t[3] = (short)f2bf(f0.w);
        t[4] = (short)f2bf(f1.x); t[5] = (short)f2bf(f1.y);
        t[6] = (short)f2bf(f1.z); t[7] = (short)f2bf(f1.w);
        b[kk] = t;
    }

    const int t0 = p * PS;
    const int t1 = min(t0 + PS, Nt);

    unsigned tvp[K_TOP];
#pragma unroll
    for (int q = 0; q < K_TOP; ++q) tvp[q] = 0u;

    const int rounds = (t1 > t0) ? ((t1 - t0 + 63) >> 6) : 0;

    if (rounds > 0) {
        stage64(htb, ldsT, t0, Nt, tid, wbase);
        __syncthreads();

        for (int rd = 0; rd < rounds; ++rd) {
            const int cur = rd & 1;
            const int tb  = t0 + rd * 64;
            if (rd + 1 < rounds)
                stage64(htb, ldsT + (cur ^ 1) * 16384, tb + 64, Nt, tid, wbase);

            const bool guard = (tb + 64 > t1);
            const short* lb = ldsT + cur * 16384;
#pragma unroll
            for (int tt = 0; tt < 2; ++tt) {
                f32x16 acc = {};
                const short* rowp = lb + (tt * 32 + l5) * CDIM;
#pragma unroll
                for (int kk = 0; kk < 16; ++kk) {
                    // A-frag: row = l5 (t-local), k = kk*16 + hi*8 + j; unswizzle granule
                    bf16x8 a = *(const bf16x8*)(rowp + (((kk * 2 + hi) ^ l5) * 8));
                    acc = __builtin_amdgcn_mfma_f32_32x32x16_bf16(a, b[kk], acc, 0, 0, 0);
                }
                // ---- packed scan: one s-col per lane, 16 t-values ----
                const int tb2 = tb + tt * 32 + 4 * hi;
                unsigned pu[16];
#pragma unroll
                for (int r = 0; r < 16; ++r) {
                    unsigned u = __float_as_uint(acc[r]);
                    u ^= (unsigned)((int)u >> 31) | 0x80000000u;   // order-preserving
                    int t = tb2 + (r & 3) + 8 * (r >> 2);
                    pu[r] = (u & 0xFFFFC000u) | (unsigned)t;       // 18 value bits | 14 idx bits
                }
                if (guard) {
#pragma unroll
                    for (int r = 0; r < 16; ++r) {
                        int t = tb2 + (r & 3) + 8 * (r >> 2);
                        if (t >= t1) pu[r] = 0u;
                    }
                }
                unsigned mx = umax16(pu);
                while (__any((int)(mx > tvp[K_TOP - 1]))) {
                    sorted_insert<K_TOP>(tvp, mx);     // no-op for lanes with mx <= tvp[9]
#pragma unroll
                    for (int r = 0; r < 16; ++r)
                        pu[r] = (pu[r] == mx) ? 0u : pu[r];
                    mx = umax16(pu);
                }
            }
            __syncthreads();
        }
    }

    // chain write: layout [prob][chain][q][Ns], coalesced across srow
    if (srow < Ns) {
        unsigned* wp = partials + ((size_t)(prob * CH + (p * 2 + hi)) * K_TOP) * Ns + srow;
#pragma unroll
        for (int q = 0; q < K_TOP; ++q) wp[(size_t)q * Ns] = tvp[q];
    }
}

// ---------- Phase 2: merge packed chains -> top-16 candidate indices ----------
__global__ void topk_mergecand(const unsigned* __restrict__ partials, int* __restrict__ cand,
                               int Ns, int CH)
{
    int g = blockIdx.x * blockDim.x + threadIdx.x;
    if (g >= 2 * Ns) return;
    const int prob = g >= Ns ? 1 : 0;
    const int row  = g - prob * Ns;
    const unsigned* src = partials + ((size_t)prob * CH * K_TOP) * Ns + row;

    unsigned tvp[CAND_M];
#pragma unroll
    for (int q = 0; q < CAND_M; ++q) tvp[q] = 0u;

    for (int c = 0; c < CH; ++c) {
#pragma unroll
        for (int q = 0; q < K_TOP; ++q) {
            unsigned v = src[(size_t)(c * K_TOP + q) * Ns];
            if (v > tvp[CAND_M - 1]) sorted_insert<CAND_M>(tvp, v);
        }
    }
    int* dst = cand + (size_t)g * CAND_M;
#pragma unroll
    for (int q = 0; q < CAND_M; ++q) dst[q] = (int)(tvp[q] & 0x3FFFu);
}

// ---------- Phase 3: f64 refine, exact sort, softmax, write ----------
__global__ __launch_bounds__(256) void topk_refine(
    const float* __restrict__ ehs, const float* __restrict__ eht,
    const float* __restrict__ rhs_, const float* __restrict__ rht,
    const int* __restrict__ cand, float* __restrict__ out, int Ns, int Nt)
{
    const int wid  = (int)((blockIdx.x * (size_t)blockDim.x + threadIdx.x) >> 6);
    const int lane = threadIdx.x & 63;
    if (wid >= 2 * Ns) return;
    const int prob = wid < Ns ? 0 : 1;
    const int row  = prob ? (wid - Ns) : wid;
    const float* hs = prob ? rhs_ : ehs;
    const float* ht = prob ? rht  : eht;

    float4 a = *(const float4*)&hs[(size_t)row * CDIM + lane * 4];
    const double a0 = a.x, a1 = a.y, a2 = a.z, a3 = a.w;

    double vd[CAND_M]; int ci[CAND_M];
#pragma unroll
    for (int m = 0; m < CAND_M; ++m) { vd[m] = -1.0e300; ci[m] = 0x7FFFFFFF; }

    const int* cbase = cand + (size_t)wid * CAND_M;
#pragma unroll
    for (int m = 0; m < CAND_M; ++m) {
        int t = cbase[m];
        if (t >= 0 && t < Nt) {
            ci[m] = t;
            float4 bb = *(const float4*)&ht[(size_t)t * CDIM + lane * 4];
            double s = a0 * (double)bb.x + a1 * (double)bb.y
                     + a2 * (double)bb.z + a3 * (double)bb.w;
#pragma unroll
            for (int d = 1; d < 64; d <<= 1) s += __shfl_xor(s, d, 64);
            vd[m] = s;
        }
    }

    if (lane == 0) {
        float ov[K_TOP]; int oi[K_TOP];
#pragma unroll
        for (int o = 0; o < K_TOP; ++o) {
            double bv = vd[0]; int bi = ci[0]; int bp = 0;
#pragma unroll
            for (int q = 1; q < CAND_M; ++q) {
                bool better = (vd[q] > bv) || (vd[q] == bv && ci[q] < bi);
                if (better) { bv = vd[q]; bi = ci[q]; bp = q; }
            }
            ov[o] = (float)bv; oi[o] = bi;
#pragma unroll
            for (int q = 0; q < CAND_M; ++q) if (q == bp) vd[q] = -1.0e301;
        }
        float m0 = ov[0], ssum = 0.f, ex[K_TOP];
#pragma unroll
        for (int q = 0; q < K_TOP; ++q) { ex[q] = __expf(ov[q] - m0); ssum += ex[q]; }
        float inv = 1.f / ssum;
        size_t nsk = (size_t)Ns * K_TOP;
        size_t so  = (size_t)wid * K_TOP;
#pragma unroll
        for (int q = 0; q < K_TOP; ++q) out[so + q] = ex[q] * inv;
#pragma unroll
        for (int q = 0; q < K_TOP; ++q) out[2 * nsk + so + q] = (float)oi[q];
    }
}

extern "C" void kernel_launch(void* const* d_in, const int* in_sizes, int n_in,
                              void* d_out, int out_size, void* d_ws, size_t ws_size,
                              hipStream_t stream) {
    (void)n_in; (void)out_size;
    const float* eh_s = (const float*)d_in[0];
    const float* eh_t = (const float*)d_in[1];
    const float* rh_s = (const float*)d_in[2];
    const float* rh_t = (const float*)d_in[3];
    // d_in[4] is k (=10), compile-time constant here.

    const int Ns = in_sizes[0] / CDIM;
    const int Nt = in_sizes[1] / CDIM;
    const int SB = (Ns + 127) / 128;

    const size_t htbElems = (size_t)Nt * CDIM;          // per array, ushorts
    const size_t htbBytes = 2 * htbElems * 2;
    const size_t candBytes = (size_t)2 * Ns * CAND_M * sizeof(int);

    int Pt = 8;
    while (Pt > 1 &&
           htbBytes + (size_t)2 * Ns * (2 * Pt) * K_TOP * sizeof(unsigned) + candBytes > ws_size)
        Pt >>= 1;
    const int PS = (int)((((size_t)Nt + Pt - 1) / Pt + 63) & ~(size_t)63);

    unsigned short* htb_e = (unsigned short*)d_ws;
    unsigned short* htb_r = htb_e + htbElems;
    unsigned* partials = (unsigned*)(htb_r + htbElems);
    int*  cand = (int*)((char*)partials + (size_t)2 * Ns * (2 * Pt) * K_TOP * sizeof(unsigned));

    dim3 block(256);

    // Phase 0: convert both h_t arrays (swizzled bf16)
    int convBlocks = (Nt * 32 + 255) / 256;
    conv_swz<<<dim3(convBlocks), block, 0, stream>>>(eh_t, htb_e, Nt);
    conv_swz<<<dim3(convBlocks), block, 0, stream>>>(rh_t, htb_r, Nt);

    // Phase 1: MFMA GEMM + packed top-10 chains
    topk_mfma<<<dim3(2 * Pt * SB), block, 0, stream>>>(eh_s, rh_s, htb_e, htb_r,
                                                       partials, Ns, Nt, Pt, SB, PS);

    // Phase 2: merge -> candidates
    int nrows = 2 * Ns;
    topk_mergecand<<<dim3((nrows + 255) / 256), block, 0, stream>>>(partials, cand,
                                                                    Ns, 2 * Pt);

    // Phase 3: f64 refine + softmax + write
    int refineBlocks = (nrows * 64 + 255) / 256;
    topk_refine<<<dim3(refineBlocks), block, 0, stream>>>(eh_s, eh_t, rh_s, rh_t,
                                                          cand, (float*)d_out, Ns, Nt);
}